// Round 2
// baseline (978.666 us; speedup 1.0000x reference)
//
#include <hip/hip_runtime.h>
#include <cstddef>

#define H      128
#define HV     32          // H/4
#define NBATCH 32
#define NN     8192
#define RTOT   (NBATCH*NN) // 262144 rows
#define NLAYER 3
#define BNEPS  1e-5f
#define NSLOT  16
#define NPB    64          // rows per conv block (divides NN)
#define NPBH   32          // rows per head block

typedef unsigned short ushort_t;

__device__ __forceinline__ float bf2f(unsigned int lo16) {
    return __uint_as_float(lo16 << 16);
}
__device__ __forceinline__ unsigned short f2bf(float f) {
    unsigned int u = __float_as_uint(f);
    u = (u + 0x7FFFu + ((u >> 16) & 1u)) >> 16;
    return (unsigned short)u;
}
__device__ __forceinline__ void unpack8(uint4 pk, float* d) {
    d[0] = bf2f(pk.x & 0xFFFFu); d[1] = bf2f(pk.x >> 16);
    d[2] = bf2f(pk.y & 0xFFFFu); d[3] = bf2f(pk.y >> 16);
    d[4] = bf2f(pk.z & 0xFFFFu); d[5] = bf2f(pk.z >> 16);
    d[6] = bf2f(pk.w & 0xFFFFu); d[7] = bf2f(pk.w >> 16);
}
__device__ __forceinline__ uint4 pack8(const float* s) {
    uint4 pk;
    pk.x = (unsigned)f2bf(s[0]) | ((unsigned)f2bf(s[1]) << 16);
    pk.y = (unsigned)f2bf(s[2]) | ((unsigned)f2bf(s[3]) << 16);
    pk.z = (unsigned)f2bf(s[4]) | ((unsigned)f2bf(s[5]) << 16);
    pk.w = (unsigned)f2bf(s[6]) | ((unsigned)f2bf(s[7]) << 16);
    return pk;
}

// ---------------- embedding: h = x @ emb_w + emb_b  (h stored bf16) ----------------
__global__ __launch_bounds__(256) void k_embed(
    const float* __restrict__ x, const float* __restrict__ ew,
    const float* __restrict__ eb, ushort_t* __restrict__ hb)
{
    int idx = blockIdx.x * 256 + threadIdx.x;   // one 4-channel group
    int r  = idx >> 5;
    int cv = idx & 31;
    float x0 = x[2 * r], x1 = x[2 * r + 1];
    float4 w0 = ((const float4*)ew)[cv];
    float4 w1 = ((const float4*)ew)[HV + cv];
    float4 bb = ((const float4*)eb)[cv];
    float o[4];
    o[0] = fmaf(x1, w1.x, fmaf(x0, w0.x, bb.x));
    o[1] = fmaf(x1, w1.y, fmaf(x0, w0.y, bb.y));
    o[2] = fmaf(x1, w1.z, fmaf(x0, w0.z, bb.z));
    o[3] = fmaf(x1, w1.w, fmaf(x0, w0.w, bb.w));
    ushort4 st;
    st.x = f2bf(o[0]); st.y = f2bf(o[1]); st.z = f2bf(o[2]); st.w = f2bf(o[3]);
    ((ushort4*)(hb + (size_t)r * H))[cv] = st;
}

// ------------- graph conv + BN stats accumulation -------------
__global__ __launch_bounds__(256) void k_conv(
    const ushort_t* __restrict__ hb, const float* __restrict__ Wl,
    const float* __restrict__ bl, const float* __restrict__ Wn,
    const float* __restrict__ bnb, const float* __restrict__ mask,
    ushort_t* __restrict__ hnb, float* __restrict__ gstats)
{
    __shared__ float hs[NPB + 2][H];   // fp32 tile, rows r0-1 .. r0+NPB (ring wrap)
    __shared__ float ls[2 * H];
    const int t  = threadIdx.x;
    const int r0 = blockIdx.x * NPB;   // never straddles a batch (NPB | NN)
    const int bb = r0 / NN;
    const int n0 = r0 - bb * NN;

    for (int i = t; i < (NPB + 2) * 16; i += 256) {   // 16 groups of 8 bf16 per row
        int row = i >> 4, g = i & 15;
        int n = n0 + row - 1;
        n = (n + NN) & (NN - 1);
        uint4 pk = *((const uint4*)(hb + ((size_t)(bb * NN + n)) * H + g * 8));
        float tmp[8];
        unpack8(pk, tmp);
        float* dst = &hs[row][g * 8];
        ((float4*)dst)[0] = make_float4(tmp[0], tmp[1], tmp[2], tmp[3]);
        ((float4*)dst)[1] = make_float4(tmp[4], tmp[5], tmp[6], tmp[7]);
    }
    __syncthreads();

    const int cg = t & 31;     // out channels cg*4..cg*4+3
    const int rg = t >> 5;     // local rows rg*8..rg*8+7
    float acc[8][4];
    #pragma unroll
    for (int j = 0; j < 8; ++j) { acc[j][0]=0.f; acc[j][1]=0.f; acc[j][2]=0.f; acc[j][3]=0.f; }

    const float4* W4  = (const float4*)Wl;
    const float4* Wn4 = (const float4*)Wn;

    for (int k0 = 0; k0 < H; k0 += 4) {
        float wv[4][4], wnv[4][4];
        #pragma unroll
        for (int kk = 0; kk < 4; ++kk) {
            float4 a = W4 [(k0 + kk) * HV + cg];
            float4 b = Wn4[(k0 + kk) * HV + cg];
            wv[kk][0]=a.x; wv[kk][1]=a.y; wv[kk][2]=a.z; wv[kk][3]=a.w;
            wnv[kk][0]=b.x; wnv[kk][1]=b.y; wnv[kk][2]=b.z; wnv[kk][3]=b.w;
        }
        float hvv[10][4];
        #pragma unroll
        for (int i = 0; i < 10; ++i) {
            float4 v = *((const float4*)(&hs[rg * 8 + i][k0]));
            hvv[i][0]=v.x; hvv[i][1]=v.y; hvv[i][2]=v.z; hvv[i][3]=v.w;
        }
        #pragma unroll
        for (int kk = 0; kk < 4; ++kk) {
            #pragma unroll
            for (int j = 0; j < 8; ++j) {
                float a  = hvv[j + 1][kk];
                float ns = hvv[j][kk] + hvv[j + 2][kk];
                #pragma unroll
                for (int q = 0; q < 4; ++q)
                    acc[j][q] = fmaf(a, wv[kk][q], fmaf(ns, wnv[kk][q], acc[j][q]));
            }
        }
    }

    float4 bl4 = ((const float4*)bl)[cg];
    float4 bn4 = ((const float4*)bnb)[cg];
    float ps[4]  = {0,0,0,0};
    float pss[4] = {0,0,0,0};
    #pragma unroll
    for (int j = 0; j < 8; ++j) {
        int gr = r0 + rg * 8 + j;
        float m = mask[gr];
        float v[4];
        v[0] = (acc[j][0] + bl4.x + bn4.x) * m;
        v[1] = (acc[j][1] + bl4.y + bn4.y) * m;
        v[2] = (acc[j][2] + bl4.z + bn4.z) * m;
        v[3] = (acc[j][3] + bl4.w + bn4.w) * m;
        ushort4 st;
        st.x = f2bf(v[0]); st.y = f2bf(v[1]); st.z = f2bf(v[2]); st.w = f2bf(v[3]);
        ((ushort4*)(hnb + (size_t)gr * H))[cg] = st;
        ps[0] += v[0]; ps[1] += v[1]; ps[2] += v[2]; ps[3] += v[3];
        pss[0] += v[0]*v[0]; pss[1] += v[1]*v[1]; pss[2] += v[2]*v[2]; pss[3] += v[3]*v[3];
    }

    ls[t] = 0.f;               // 2*H == 256 == blockDim
    __syncthreads();
    #pragma unroll
    for (int q = 0; q < 4; ++q) {
        atomicAdd(&ls[cg * 4 + q],     ps[q]);
        atomicAdd(&ls[H + cg * 4 + q], pss[q]);
    }
    __syncthreads();
    int slot = blockIdx.x & (NSLOT - 1);
    atomicAdd(&gstats[slot * 2 * H + t], ls[t]);
}

// ------------- BN stats finalize -------------
__global__ void k_bnstats(const float* __restrict__ gstats,
                          const float* __restrict__ g, const float* __restrict__ b,
                          float* __restrict__ scl, float* __restrict__ sft)
{
    int c = threadIdx.x;       // H threads
    float s = 0.f, ss = 0.f;
    for (int i = 0; i < NSLOT; ++i) {
        s  += gstats[i * 2 * H + c];
        ss += gstats[i * 2 * H + H + c];
    }
    const float invR = 1.f / (float)RTOT;
    float mean = s * invR;
    float var  = ss * invR - mean * mean;
    float inv  = rsqrtf(var + BNEPS);
    float sc   = g[c] * inv;
    scl[c] = sc;
    sft[c] = fmaf(-mean, sc, b[c]);
}

// ------------- h += relu(hn*scl + sft)  (bf16 in/out, 8 elems/thread) -------------
__global__ __launch_bounds__(256) void k_norm_res(
    const ushort_t* __restrict__ hnb, const float* __restrict__ scl,
    const float* __restrict__ sft, ushort_t* __restrict__ hb)
{
    int idx = blockIdx.x * 256 + threadIdx.x;   // one 8-channel group
    int row = idx >> 4;
    int g   = idx & 15;
    uint4 pn = *((const uint4*)(hnb + (size_t)row * H + g * 8));
    uint4 ph = *((const uint4*)(hb  + (size_t)row * H + g * 8));
    float vn[8], vh[8];
    unpack8(pn, vn);
    unpack8(ph, vh);
    float4 s0 = ((const float4*)scl)[g * 2],     s1 = ((const float4*)scl)[g * 2 + 1];
    float4 f0 = ((const float4*)sft)[g * 2],     f1 = ((const float4*)sft)[g * 2 + 1];
    float sa[8] = {s0.x,s0.y,s0.z,s0.w,s1.x,s1.y,s1.z,s1.w};
    float fa[8] = {f0.x,f0.y,f0.z,f0.w,f1.x,f1.y,f1.z,f1.w};
    #pragma unroll
    for (int e = 0; e < 8; ++e)
        vh[e] += fmaxf(fmaf(vn[e], sa[e], fa[e]), 0.f);
    *((uint4*)(hb + (size_t)row * H + g * 8)) = pack8(vh);
}

// ------------- head: out = (relu(h@W1 + b1) @ W2 + b2) * m -------------
__global__ __launch_bounds__(256) void k_head(
    const ushort_t* __restrict__ hb, const float* __restrict__ W1,
    const float* __restrict__ b1, const float* __restrict__ W2,
    const float* __restrict__ b2, const float* __restrict__ mask,
    float* __restrict__ out)
{
    __shared__ float hs[NPBH][H + 4];   // 16.9 KiB
    __shared__ float w1s[H][64];        // 32 KiB
    const int t = threadIdx.x;
    const size_t r0 = (size_t)blockIdx.x * NPBH;

    for (int i = t; i < H * 16; i += 256)     // stage W1 (128x64)
        ((float4*)w1s)[i] = ((const float4*)W1)[i];
    for (int i = t; i < NPBH * 16; i += 256) {  // stage h rows (bf16 -> fp32)
        int row = i >> 4, g = i & 15;
        uint4 pk = *((const uint4*)(hb + (r0 + row) * H + g * 8));
        float tmp[8];
        unpack8(pk, tmp);
        float* dst = &hs[row][g * 8];
        ((float4*)dst)[0] = make_float4(tmp[0], tmp[1], tmp[2], tmp[3]);
        ((float4*)dst)[1] = make_float4(tmp[4], tmp[5], tmp[6], tmp[7]);
    }
    __syncthreads();

    const int rl = t >> 3;     // local row (0..31)
    const int cg = t & 7;      // hidden channels cg*8..cg*8+7
    float acc[8];
    #pragma unroll
    for (int q = 0; q < 8; ++q) acc[q] = 0.f;

    for (int k0 = 0; k0 < H; k0 += 4) {
        float4 a4 = *((const float4*)&hs[rl][k0]);
        float av[4] = {a4.x, a4.y, a4.z, a4.w};
        #pragma unroll
        for (int kk = 0; kk < 4; ++kk) {
            #pragma unroll
            for (int q = 0; q < 2; ++q) {
                float4 w = ((float4*)(&w1s[k0 + kk][0]))[cg * 2 + q];
                acc[q*4+0] = fmaf(av[kk], w.x, acc[q*4+0]);
                acc[q*4+1] = fmaf(av[kk], w.y, acc[q*4+1]);
                acc[q*4+2] = fmaf(av[kk], w.z, acc[q*4+2]);
                acc[q*4+3] = fmaf(av[kk], w.w, acc[q*4+3]);
            }
        }
    }

    float p0 = 0.f, p1 = 0.f;
    #pragma unroll
    for (int q = 0; q < 8; ++q) {
        int c = cg * 8 + q;
        float v = fmaxf(acc[q] + b1[c], 0.f);
        p0 = fmaf(v, W2[2*c],     p0);
        p1 = fmaf(v, W2[2*c + 1], p1);
    }
    p0 += __shfl_xor(p0, 1); p0 += __shfl_xor(p0, 2); p0 += __shfl_xor(p0, 4);
    p1 += __shfl_xor(p1, 1); p1 += __shfl_xor(p1, 2); p1 += __shfl_xor(p1, 4);
    if (cg == 0) {
        size_t gr = r0 + rl;
        float m = mask[gr];
        out[2*gr]     = (p0 + b2[0]) * m;
        out[2*gr + 1] = (p1 + b2[1]) * m;
    }
}

extern "C" void kernel_launch(void* const* d_in, const int* in_sizes, int n_in,
                              void* d_out, int out_size, void* d_ws, size_t ws_size,
                              hipStream_t stream)
{
    const float* x     = (const float*)d_in[0];
    const float* mask  = (const float*)d_in[1];
    const float* emb_w = (const float*)d_in[2];
    const float* emb_b = (const float*)d_in[3];
    const float* lin_w = (const float*)d_in[4];
    const float* lin_b = (const float*)d_in[5];
    const float* nb_w  = (const float*)d_in[6];
    const float* nb_b  = (const float*)d_in[7];
    const float* bn_g  = (const float*)d_in[8];
    const float* bn_b  = (const float*)d_in[9];
    const float* o1w   = (const float*)d_in[10];
    const float* o1b   = (const float*)d_in[11];
    const float* o2w   = (const float*)d_in[12];
    const float* o2b   = (const float*)d_in[13];
    float* out = (float*)d_out;

    // Workspace: h (bf16, 64 MiB) + hn (bf16, 64 MiB) = 128 MiB total.
    char* ws = (char*)d_ws;
    ushort_t* hb  = (ushort_t*)ws;
    ushort_t* hnb = (ushort_t*)(ws + (size_t)RTOT * H * 2);

    // BN stats scratch lives in d_out (2 MiB; fully overwritten by k_head last).
    float* gst = (float*)d_out;                       // NLAYER*NSLOT*2*H = 12288 floats
    float* scl = gst + NLAYER * NSLOT * 2 * H;        // NLAYER*H
    float* sft = scl + NLAYER * H;                    // NLAYER*H

    hipMemsetAsync(gst, 0, NLAYER * NSLOT * 2 * H * sizeof(float), stream);

    k_embed<<<RTOT * HV / 256, 256, 0, stream>>>(x, emb_w, emb_b, hb);
    for (int i = 0; i < NLAYER; ++i) {
        k_conv<<<RTOT / NPB, 256, 0, stream>>>(
            hb, lin_w + i * H * H, lin_b + i * H,
            nb_w + i * H * H, nb_b + i * H, mask,
            hnb, gst + i * NSLOT * 2 * H);
        k_bnstats<<<1, H, 0, stream>>>(
            gst + i * NSLOT * 2 * H, bn_g + i * H, bn_b + i * H,
            scl + i * H, sft + i * H);
        k_norm_res<<<RTOT * H / 8 / 256, 256, 0, stream>>>(
            hnb, scl + i * H, sft + i * H, hb);
    }
    k_head<<<RTOT / NPBH, 256, 0, stream>>>(hb, o1w, o1b, o2w, o2b, mask, out);
}

// Round 3
// 450.723 us; speedup vs baseline: 2.1713x; 2.1713x over previous
//
#include <hip/hip_runtime.h>
#include <cstddef>

#define H      128
#define HV     32
#define NBATCH 32
#define NN     8192
#define RTOT   (NBATCH*NN) // 262144 rows
#define NLAYER 3
#define BNEPS  1e-5f
#define NSLOT  16
#define NPB    64          // rows per conv block (divides NN)
#define NPBH   32          // rows per head block
#define HS_STRIDE 136      // bf16 elems per LDS row (128 + 8 pad)
#define TR_STRIDE 132      // fp32 elems per transpose row (128 + 4 pad)

typedef unsigned short ushort_t;
typedef __attribute__((ext_vector_type(8))) short short8;   // 8 bf16 (4 VGPRs)
typedef __attribute__((ext_vector_type(4))) float f32x4;    // MFMA C/D

__device__ __forceinline__ float bf2f(unsigned int lo16) {
    return __uint_as_float(lo16 << 16);
}
__device__ __forceinline__ unsigned short f2bf(float f) {
    unsigned int u = __float_as_uint(f);
    u = (u + 0x7FFFu + ((u >> 16) & 1u)) >> 16;
    return (unsigned short)u;
}
__device__ __forceinline__ void unpack8(uint4 pk, float* d) {
    d[0] = bf2f(pk.x & 0xFFFFu); d[1] = bf2f(pk.x >> 16);
    d[2] = bf2f(pk.y & 0xFFFFu); d[3] = bf2f(pk.y >> 16);
    d[4] = bf2f(pk.z & 0xFFFFu); d[5] = bf2f(pk.z >> 16);
    d[6] = bf2f(pk.w & 0xFFFFu); d[7] = bf2f(pk.w >> 16);
}
__device__ __forceinline__ uint4 pack8(const float* s) {
    uint4 pk;
    pk.x = (unsigned)f2bf(s[0]) | ((unsigned)f2bf(s[1]) << 16);
    pk.y = (unsigned)f2bf(s[2]) | ((unsigned)f2bf(s[3]) << 16);
    pk.z = (unsigned)f2bf(s[4]) | ((unsigned)f2bf(s[5]) << 16);
    pk.w = (unsigned)f2bf(s[6]) | ((unsigned)f2bf(s[7]) << 16);
    return pk;
}

// ---- weight prep: fp32 W[l][k][n] -> bf16 Wt[l][n][k] (B^T fragment layout) ----
__global__ __launch_bounds__(256) void k_prep(
    const float* __restrict__ lin_w, const float* __restrict__ nb_w,
    ushort_t* __restrict__ Wlt, ushort_t* __restrict__ Wnt)
{
    int id = blockIdx.x * 256 + threadIdx.x;    // 2*3*128*128 = 98304 total
    int mat = id / 49152;
    int r   = id - mat * 49152;
    int l   = r >> 14;
    int r2  = r & 16383;
    int k   = r2 >> 7;
    int n   = r2 & 127;                          // fastest -> coalesced reads
    const float* src = mat ? nb_w : lin_w;
    ushort_t*    dst = mat ? Wnt  : Wlt;
    dst[l * 16384 + n * 128 + k] = f2bf(src[l * 16384 + k * 128 + n]);
}

// ---------------- embedding: h = x @ emb_w + emb_b  (h stored bf16) ----------------
__global__ __launch_bounds__(256) void k_embed(
    const float* __restrict__ x, const float* __restrict__ ew,
    const float* __restrict__ eb, ushort_t* __restrict__ hb)
{
    int idx = blockIdx.x * 256 + threadIdx.x;
    int r  = idx >> 5;
    int cv = idx & 31;
    float x0 = x[2 * r], x1 = x[2 * r + 1];
    float4 w0 = ((const float4*)ew)[cv];
    float4 w1 = ((const float4*)ew)[HV + cv];
    float4 bb = ((const float4*)eb)[cv];
    float o[4];
    o[0] = fmaf(x1, w1.x, fmaf(x0, w0.x, bb.x));
    o[1] = fmaf(x1, w1.y, fmaf(x0, w0.y, bb.y));
    o[2] = fmaf(x1, w1.z, fmaf(x0, w0.z, bb.z));
    o[3] = fmaf(x1, w1.w, fmaf(x0, w0.w, bb.w));
    ushort4 st;
    st.x = f2bf(o[0]); st.y = f2bf(o[1]); st.z = f2bf(o[2]); st.w = f2bf(o[3]);
    ((ushort4*)(hb + (size_t)r * H))[cv] = st;
}

// ------------- MFMA graph conv + BN stats -------------
// Block: 64 rows x 128 cols, 4 waves (each wave: 64 rows x 32 cols).
__global__ __launch_bounds__(256) void k_conv(
    const ushort_t* __restrict__ hb,
    const ushort_t* __restrict__ Wlt, const ushort_t* __restrict__ Wnt,
    const float* __restrict__ bl, const float* __restrict__ bnb,
    const float* __restrict__ mask,
    ushort_t* __restrict__ hnb, float* __restrict__ gstats)
{
    // union: [hs 66 rows | ns 64 rows] bf16 during MFMA phase; tr (fp32) after.
    __shared__ __align__(16) char smem[66 * HS_STRIDE * 2 + 64 * HS_STRIDE * 2];
    __shared__ float msk[NPB];
    ushort_t* hs = (ushort_t*)smem;                    // rows r0-1 .. r0+64
    ushort_t* ns = hs + 66 * HS_STRIDE;                // nsum rows r0 .. r0+63
    float*    tr = (float*)smem;                       // 64 x TR_STRIDE (reuse)

    const int t    = threadIdx.x;
    const int wave = t >> 6;
    const int lane = t & 63;
    const int l15  = lane & 15;
    const int quad = lane >> 4;
    const int r0   = blockIdx.x * NPB;
    const int batch = r0 / NN;
    const int n0   = r0 - batch * NN;

    // --- B fragments: Wt[n][k], lane reads 8 contiguous k at row nbase+l15 ---
    const int colbase = wave * 32;
    short8 bWl[2][4], bWn[2][4];
    #pragma unroll
    for (int nt = 0; nt < 2; ++nt) {
        int nrow = colbase + nt * 16 + l15;
        #pragma unroll
        for (int ks = 0; ks < 4; ++ks) {
            int off = nrow * 128 + ks * 32 + quad * 8;
            bWl[nt][ks] = *((const short8*)(Wlt + off));
            bWn[nt][ks] = *((const short8*)(Wnt + off));
        }
    }

    // --- stage h rows (bf16, padded stride) ---
    for (int i = t; i < 66 * 16; i += 256) {
        int row = i >> 4, g = i & 15;
        int n = n0 + row - 1;
        n = (n + NN) & (NN - 1);
        uint4 pk = *((const uint4*)(hb + ((size_t)(batch * NN + n)) * H + g * 8));
        *((uint4*)(hs + row * HS_STRIDE + g * 8)) = pk;
    }
    if (t < NPB) msk[t] = mask[r0 + t];
    __syncthreads();

    // --- nsum rows in bf16: ns[r] = hs[r] + hs[r+2]  (packed dword math) ---
    {
        const unsigned* hsu = (const unsigned*)hs;
        unsigned* nsu = (unsigned*)ns;
        for (int i = t; i < 64 * 32; i += 256) {       // 32 dword-pairs per row
            int row = i >> 5, dw = (i & 31) * 2;
            uint2 a = *((const uint2*)(hsu + row * 68 + dw));
            uint2 b = *((const uint2*)(hsu + (row + 2) * 68 + dw));
            uint2 o;
            float s0 = bf2f(a.x & 0xFFFFu) + bf2f(b.x & 0xFFFFu);
            float s1 = bf2f(a.x >> 16)     + bf2f(b.x >> 16);
            float s2 = bf2f(a.y & 0xFFFFu) + bf2f(b.y & 0xFFFFu);
            float s3 = bf2f(a.y >> 16)     + bf2f(b.y >> 16);
            o.x = (unsigned)f2bf(s0) | ((unsigned)f2bf(s1) << 16);
            o.y = (unsigned)f2bf(s2) | ((unsigned)f2bf(s3) << 16);
            *((uint2*)(nsu + row * 68 + dw)) = o;
        }
    }
    __syncthreads();

    // --- MFMA K-loop ---
    f32x4 acc[4][2];
    #pragma unroll
    for (int mt = 0; mt < 4; ++mt)
        #pragma unroll
        for (int nt = 0; nt < 2; ++nt)
            acc[mt][nt] = (f32x4){0.f, 0.f, 0.f, 0.f};

    #pragma unroll
    for (int ks = 0; ks < 4; ++ks) {
        short8 as[4], an[4];
        #pragma unroll
        for (int mt = 0; mt < 4; ++mt) {
            int row = mt * 16 + l15;
            as[mt] = *((const short8*)(hs + (row + 1) * HS_STRIDE + ks * 32 + quad * 8));
            an[mt] = *((const short8*)(ns + row * HS_STRIDE + ks * 32 + quad * 8));
        }
        #pragma unroll
        for (int nt = 0; nt < 2; ++nt)
            #pragma unroll
            for (int mt = 0; mt < 4; ++mt)
                acc[mt][nt] = __builtin_amdgcn_mfma_f32_16x16x32_bf16(
                    as[mt], bWl[nt][ks], acc[mt][nt], 0, 0, 0);
        #pragma unroll
        for (int nt = 0; nt < 2; ++nt)
            #pragma unroll
            for (int mt = 0; mt < 4; ++mt)
                acc[mt][nt] = __builtin_amdgcn_mfma_f32_16x16x32_bf16(
                    an[mt], bWn[nt][ks], acc[mt][nt], 0, 0, 0);
    }
    __syncthreads();   // hs/ns dead; tr may now overwrite

    // --- epilogue: bias + mask, BN partials, transpose via LDS ---
    float s[2] = {0.f, 0.f}, ss[2] = {0.f, 0.f};
    #pragma unroll
    for (int nt = 0; nt < 2; ++nt) {
        int col = colbase + nt * 16 + l15;
        float bsum = bl[col] + bnb[col];
        #pragma unroll
        for (int mt = 0; mt < 4; ++mt) {
            #pragma unroll
            for (int reg = 0; reg < 4; ++reg) {
                int lrow = mt * 16 + quad * 4 + reg;
                float v = (acc[mt][nt][reg] + bsum) * msk[lrow];
                tr[lrow * TR_STRIDE + col] = v;
                s[nt] += v;
                ss[nt] += v * v;
            }
        }
    }
    #pragma unroll
    for (int nt = 0; nt < 2; ++nt) {
        s[nt]  += __shfl_xor(s[nt], 16);  s[nt]  += __shfl_xor(s[nt], 32);
        ss[nt] += __shfl_xor(ss[nt], 16); ss[nt] += __shfl_xor(ss[nt], 32);
    }
    int slot = blockIdx.x & (NSLOT - 1);
    if (lane < 16) {
        #pragma unroll
        for (int nt = 0; nt < 2; ++nt) {
            int col = colbase + nt * 16 + lane;
            atomicAdd(&gstats[slot * 2 * H + col],     s[nt]);
            atomicAdd(&gstats[slot * 2 * H + H + col], ss[nt]);
        }
    }
    __syncthreads();

    // --- coalesced bf16 writeback ---
    for (int i = t; i < 64 * 16; i += 256) {
        int row = i >> 4, g = i & 15;
        const float* src = tr + row * TR_STRIDE + g * 8;
        float tmp[8];
        float4 v0 = ((const float4*)src)[0];
        float4 v1 = ((const float4*)src)[1];
        tmp[0]=v0.x; tmp[1]=v0.y; tmp[2]=v0.z; tmp[3]=v0.w;
        tmp[4]=v1.x; tmp[5]=v1.y; tmp[6]=v1.z; tmp[7]=v1.w;
        *((uint4*)(hnb + (size_t)(r0 + row) * H + g * 8)) = pack8(tmp);
    }
}

// ------------- BN stats finalize -------------
__global__ void k_bnstats(const float* __restrict__ gstats,
                          const float* __restrict__ g, const float* __restrict__ b,
                          float* __restrict__ scl, float* __restrict__ sft)
{
    int c = threadIdx.x;
    float s = 0.f, ss = 0.f;
    for (int i = 0; i < NSLOT; ++i) {
        s  += gstats[i * 2 * H + c];
        ss += gstats[i * 2 * H + H + c];
    }
    const float invR = 1.f / (float)RTOT;
    float mean = s * invR;
    float var  = ss * invR - mean * mean;
    float inv  = rsqrtf(var + BNEPS);
    float sc   = g[c] * inv;
    scl[c] = sc;
    sft[c] = fmaf(-mean, sc, b[c]);
}

// ------------- h += relu(hn*scl + sft) -------------
__global__ __launch_bounds__(256) void k_norm_res(
    const ushort_t* __restrict__ hnb, const float* __restrict__ scl,
    const float* __restrict__ sft, ushort_t* __restrict__ hb)
{
    int idx = blockIdx.x * 256 + threadIdx.x;
    int row = idx >> 4;
    int g   = idx & 15;
    uint4 pn = *((const uint4*)(hnb + (size_t)row * H + g * 8));
    uint4 ph = *((const uint4*)(hb  + (size_t)row * H + g * 8));
    float vn[8], vh[8];
    unpack8(pn, vn);
    unpack8(ph, vh);
    float4 s0 = ((const float4*)scl)[g * 2], s1 = ((const float4*)scl)[g * 2 + 1];
    float4 f0 = ((const float4*)sft)[g * 2], f1 = ((const float4*)sft)[g * 2 + 1];
    float sa[8] = {s0.x,s0.y,s0.z,s0.w,s1.x,s1.y,s1.z,s1.w};
    float fa[8] = {f0.x,f0.y,f0.z,f0.w,f1.x,f1.y,f1.z,f1.w};
    #pragma unroll
    for (int e = 0; e < 8; ++e)
        vh[e] += fmaxf(fmaf(vn[e], sa[e], fa[e]), 0.f);
    *((uint4*)(hb + (size_t)row * H + g * 8)) = pack8(vh);
}

// ------------- head: out = (relu(h@W1 + b1) @ W2 + b2) * m -------------
__global__ __launch_bounds__(256) void k_head(
    const ushort_t* __restrict__ hb, const float* __restrict__ W1,
    const float* __restrict__ b1, const float* __restrict__ W2,
    const float* __restrict__ b2, const float* __restrict__ mask,
    float* __restrict__ out)
{
    __shared__ float hs[NPBH][H + 4];
    __shared__ float w1s[H][64];
    const int t = threadIdx.x;
    const size_t r0 = (size_t)blockIdx.x * NPBH;

    for (int i = t; i < H * 16; i += 256)
        ((float4*)w1s)[i] = ((const float4*)W1)[i];
    for (int i = t; i < NPBH * 16; i += 256) {
        int row = i >> 4, g = i & 15;
        uint4 pk = *((const uint4*)(hb + (r0 + row) * H + g * 8));
        float tmp[8];
        unpack8(pk, tmp);
        float* dst = &hs[row][g * 8];
        ((float4*)dst)[0] = make_float4(tmp[0], tmp[1], tmp[2], tmp[3]);
        ((float4*)dst)[1] = make_float4(tmp[4], tmp[5], tmp[6], tmp[7]);
    }
    __syncthreads();

    const int rl = t >> 3;
    const int cg = t & 7;
    float acc[8];
    #pragma unroll
    for (int q = 0; q < 8; ++q) acc[q] = 0.f;

    for (int k0 = 0; k0 < H; k0 += 4) {
        float4 a4 = *((const float4*)&hs[rl][k0]);
        float av[4] = {a4.x, a4.y, a4.z, a4.w};
        #pragma unroll
        for (int kk = 0; kk < 4; ++kk) {
            #pragma unroll
            for (int q = 0; q < 2; ++q) {
                float4 w = ((float4*)(&w1s[k0 + kk][0]))[cg * 2 + q];
                acc[q*4+0] = fmaf(av[kk], w.x, acc[q*4+0]);
                acc[q*4+1] = fmaf(av[kk], w.y, acc[q*4+1]);
                acc[q*4+2] = fmaf(av[kk], w.z, acc[q*4+2]);
                acc[q*4+3] = fmaf(av[kk], w.w, acc[q*4+3]);
            }
        }
    }

    float p0 = 0.f, p1 = 0.f;
    #pragma unroll
    for (int q = 0; q < 8; ++q) {
        int c = cg * 8 + q;
        float v = fmaxf(acc[q] + b1[c], 0.f);
        p0 = fmaf(v, W2[2*c],     p0);
        p1 = fmaf(v, W2[2*c + 1], p1);
    }
    p0 += __shfl_xor(p0, 1); p0 += __shfl_xor(p0, 2); p0 += __shfl_xor(p0, 4);
    p1 += __shfl_xor(p1, 1); p1 += __shfl_xor(p1, 2); p1 += __shfl_xor(p1, 4);
    if (cg == 0) {
        size_t gr = r0 + rl;
        float m = mask[gr];
        out[2*gr]     = (p0 + b2[0]) * m;
        out[2*gr + 1] = (p1 + b2[1]) * m;
    }
}

extern "C" void kernel_launch(void* const* d_in, const int* in_sizes, int n_in,
                              void* d_out, int out_size, void* d_ws, size_t ws_size,
                              hipStream_t stream)
{
    const float* x     = (const float*)d_in[0];
    const float* mask  = (const float*)d_in[1];
    const float* emb_w = (const float*)d_in[2];
    const float* emb_b = (const float*)d_in[3];
    const float* lin_w = (const float*)d_in[4];
    const float* lin_b = (const float*)d_in[5];
    const float* nb_w  = (const float*)d_in[6];
    const float* nb_b  = (const float*)d_in[7];
    const float* bn_g  = (const float*)d_in[8];
    const float* bn_b  = (const float*)d_in[9];
    const float* o1w   = (const float*)d_in[10];
    const float* o1b   = (const float*)d_in[11];
    const float* o2w   = (const float*)d_in[12];
    const float* o2b   = (const float*)d_in[13];
    float* out = (float*)d_out;

    // Workspace: h (bf16, 64 MiB) + hn (bf16, 64 MiB).
    char* ws = (char*)d_ws;
    ushort_t* hb  = (ushort_t*)ws;
    ushort_t* hnb = (ushort_t*)(ws + (size_t)RTOT * H * 2);

    // Scratch in d_out (2 MiB, fully overwritten by k_head at the end):
    // [0, 12288): gstats; [12288, 13056): scl/sft; [65536 floats ..): bf16 Wt.
    float* gst = (float*)d_out;
    float* scl = gst + NLAYER * NSLOT * 2 * H;
    float* sft = scl + NLAYER * H;
    ushort_t* Wlt = (ushort_t*)((float*)d_out + 65536);        // 3*128*128 bf16
    ushort_t* Wnt = Wlt + NLAYER * H * H;

    hipMemsetAsync(gst, 0, NLAYER * NSLOT * 2 * H * sizeof(float), stream);

    k_prep<<<384, 256, 0, stream>>>(lin_w, nb_w, Wlt, Wnt);
    k_embed<<<RTOT * HV / 256, 256, 0, stream>>>(x, emb_w, emb_b, hb);
    for (int i = 0; i < NLAYER; ++i) {
        k_conv<<<RTOT / NPB, 256, 0, stream>>>(
            hb, Wlt + i * H * H, Wnt + i * H * H,
            lin_b + i * H, nb_b + i * H, mask,
            hnb, gst + i * NSLOT * 2 * H);
        k_bnstats<<<1, H, 0, stream>>>(
            gst + i * NSLOT * 2 * H, bn_g + i * H, bn_b + i * H,
            scl + i * H, sft + i * H);
        k_norm_res<<<RTOT * H / 8 / 256, 256, 0, stream>>>(
            hnb, scl + i * H, sft + i * H, hb);
    }
    k_head<<<RTOT / NPBH, 256, 0, stream>>>(hb, o1w, o1b, o2w, o2b, mask, out);
}

// Round 4
// 396.437 us; speedup vs baseline: 2.4687x; 1.1369x over previous
//
#include <hip/hip_runtime.h>
#include <cstddef>

#define H      128
#define HV     32
#define NBATCH 32
#define NN     8192
#define RTOT   (NBATCH*NN) // 262144 rows
#define NLAYER 3
#define BNEPS  1e-5f
#define NSLOT  16
#define NPB    64          // rows per conv/head block (divides NN)
#define HS_STRIDE 136      // bf16 elems per LDS row (128 + 8 pad)
#define TR_STRIDE 132      // fp32 elems per transpose row (128 + 4 pad)

typedef unsigned short ushort_t;
typedef __attribute__((ext_vector_type(8))) short short8;   // 8 bf16 (4 VGPRs)
typedef __attribute__((ext_vector_type(4))) float f32x4;    // MFMA C/D

__device__ __forceinline__ float bf2f(unsigned int lo16) {
    return __uint_as_float(lo16 << 16);
}
__device__ __forceinline__ unsigned short f2bf(float f) {
    unsigned int u = __float_as_uint(f);
    u = (u + 0x7FFFu + ((u >> 16) & 1u)) >> 16;
    return (unsigned short)u;
}
__device__ __forceinline__ void unpack8(uint4 pk, float* d) {
    d[0] = bf2f(pk.x & 0xFFFFu); d[1] = bf2f(pk.x >> 16);
    d[2] = bf2f(pk.y & 0xFFFFu); d[3] = bf2f(pk.y >> 16);
    d[4] = bf2f(pk.z & 0xFFFFu); d[5] = bf2f(pk.z >> 16);
    d[6] = bf2f(pk.w & 0xFFFFu); d[7] = bf2f(pk.w >> 16);
}
__device__ __forceinline__ uint4 pack8(const float* s) {
    uint4 pk;
    pk.x = (unsigned)f2bf(s[0]) | ((unsigned)f2bf(s[1]) << 16);
    pk.y = (unsigned)f2bf(s[2]) | ((unsigned)f2bf(s[3]) << 16);
    pk.z = (unsigned)f2bf(s[4]) | ((unsigned)f2bf(s[5]) << 16);
    pk.w = (unsigned)f2bf(s[6]) | ((unsigned)f2bf(s[7]) << 16);
    return pk;
}

// ---- weight prep: fp32 W[l][k][n] -> bf16 Wt[l][n][k] (B^T fragment layout) ----
__global__ __launch_bounds__(256) void k_prep(
    const float* __restrict__ lin_w, const float* __restrict__ nb_w,
    ushort_t* __restrict__ Wlt, ushort_t* __restrict__ Wnt)
{
    int id = blockIdx.x * 256 + threadIdx.x;    // 2*3*128*128 = 98304 total
    int mat = id / 49152;
    int r   = id - mat * 49152;
    int l   = r >> 14;
    int r2  = r & 16383;
    int k   = r2 >> 7;
    int n   = r2 & 127;
    const float* src = mat ? nb_w : lin_w;
    ushort_t*    dst = mat ? Wnt  : Wlt;
    dst[l * 16384 + n * 128 + k] = f2bf(src[l * 16384 + k * 128 + n]);
}

// ---------------- embedding: h = x @ emb_w + emb_b  (h stored bf16) ----------------
__global__ __launch_bounds__(256) void k_embed(
    const float* __restrict__ x, const float* __restrict__ ew,
    const float* __restrict__ eb, ushort_t* __restrict__ hb)
{
    int idx = blockIdx.x * 256 + threadIdx.x;
    int r  = idx >> 5;
    int cv = idx & 31;
    float x0 = x[2 * r], x1 = x[2 * r + 1];
    float4 w0 = ((const float4*)ew)[cv];
    float4 w1 = ((const float4*)ew)[HV + cv];
    float4 bb = ((const float4*)eb)[cv];
    float o[4];
    o[0] = fmaf(x1, w1.x, fmaf(x0, w0.x, bb.x));
    o[1] = fmaf(x1, w1.y, fmaf(x0, w0.y, bb.y));
    o[2] = fmaf(x1, w1.z, fmaf(x0, w0.z, bb.z));
    o[3] = fmaf(x1, w1.w, fmaf(x0, w0.w, bb.w));
    ushort4 st;
    st.x = f2bf(o[0]); st.y = f2bf(o[1]); st.z = f2bf(o[2]); st.w = f2bf(o[3]);
    ((ushort4*)(hb + (size_t)r * H))[cv] = st;
}

// ------------- MFMA graph conv + BN stats -------------
__global__ __launch_bounds__(256) void k_conv(
    const ushort_t* __restrict__ hb,
    const ushort_t* __restrict__ Wlt, const ushort_t* __restrict__ Wnt,
    const float* __restrict__ bl, const float* __restrict__ bnb,
    const float* __restrict__ mask,
    ushort_t* __restrict__ hnb, float* __restrict__ gstats)
{
    __shared__ __align__(16) char smem[66 * HS_STRIDE * 2 + 64 * HS_STRIDE * 2];
    __shared__ float msk[NPB];
    ushort_t* hs = (ushort_t*)smem;
    ushort_t* ns = hs + 66 * HS_STRIDE;
    float*    tr = (float*)smem;

    const int t    = threadIdx.x;
    const int wave = t >> 6;
    const int lane = t & 63;
    const int l15  = lane & 15;
    const int quad = lane >> 4;
    const int r0   = blockIdx.x * NPB;
    const int batch = r0 / NN;
    const int n0   = r0 - batch * NN;

    const int colbase = wave * 32;
    short8 bWl[2][4], bWn[2][4];
    #pragma unroll
    for (int nt = 0; nt < 2; ++nt) {
        int nrow = colbase + nt * 16 + l15;
        #pragma unroll
        for (int ks = 0; ks < 4; ++ks) {
            int off = nrow * 128 + ks * 32 + quad * 8;
            bWl[nt][ks] = *((const short8*)(Wlt + off));
            bWn[nt][ks] = *((const short8*)(Wnt + off));
        }
    }

    for (int i = t; i < 66 * 16; i += 256) {
        int row = i >> 4, g = i & 15;
        int n = n0 + row - 1;
        n = (n + NN) & (NN - 1);
        uint4 pk = *((const uint4*)(hb + ((size_t)(batch * NN + n)) * H + g * 8));
        *((uint4*)(hs + row * HS_STRIDE + g * 8)) = pk;
    }
    if (t < NPB) msk[t] = mask[r0 + t];
    __syncthreads();

    {
        const unsigned* hsu = (const unsigned*)hs;
        unsigned* nsu = (unsigned*)ns;
        for (int i = t; i < 64 * 32; i += 256) {
            int row = i >> 5, dw = (i & 31) * 2;
            uint2 a = *((const uint2*)(hsu + row * 68 + dw));
            uint2 b = *((const uint2*)(hsu + (row + 2) * 68 + dw));
            uint2 o;
            float s0 = bf2f(a.x & 0xFFFFu) + bf2f(b.x & 0xFFFFu);
            float s1 = bf2f(a.x >> 16)     + bf2f(b.x >> 16);
            float s2 = bf2f(a.y & 0xFFFFu) + bf2f(b.y & 0xFFFFu);
            float s3 = bf2f(a.y >> 16)     + bf2f(b.y >> 16);
            o.x = (unsigned)f2bf(s0) | ((unsigned)f2bf(s1) << 16);
            o.y = (unsigned)f2bf(s2) | ((unsigned)f2bf(s3) << 16);
            *((uint2*)(nsu + row * 68 + dw)) = o;
        }
    }
    __syncthreads();

    f32x4 acc[4][2];
    #pragma unroll
    for (int mt = 0; mt < 4; ++mt)
        #pragma unroll
        for (int nt = 0; nt < 2; ++nt)
            acc[mt][nt] = (f32x4){0.f, 0.f, 0.f, 0.f};

    #pragma unroll
    for (int ks = 0; ks < 4; ++ks) {
        short8 as[4], an[4];
        #pragma unroll
        for (int mt = 0; mt < 4; ++mt) {
            int row = mt * 16 + l15;
            as[mt] = *((const short8*)(hs + (row + 1) * HS_STRIDE + ks * 32 + quad * 8));
            an[mt] = *((const short8*)(ns + row * HS_STRIDE + ks * 32 + quad * 8));
        }
        #pragma unroll
        for (int nt = 0; nt < 2; ++nt)
            #pragma unroll
            for (int mt = 0; mt < 4; ++mt)
                acc[mt][nt] = __builtin_amdgcn_mfma_f32_16x16x32_bf16(
                    as[mt], bWl[nt][ks], acc[mt][nt], 0, 0, 0);
        #pragma unroll
        for (int nt = 0; nt < 2; ++nt)
            #pragma unroll
            for (int mt = 0; mt < 4; ++mt)
                acc[mt][nt] = __builtin_amdgcn_mfma_f32_16x16x32_bf16(
                    an[mt], bWn[nt][ks], acc[mt][nt], 0, 0, 0);
    }
    __syncthreads();

    float s[2] = {0.f, 0.f}, ss[2] = {0.f, 0.f};
    #pragma unroll
    for (int nt = 0; nt < 2; ++nt) {
        int col = colbase + nt * 16 + l15;
        float bsum = bl[col] + bnb[col];
        #pragma unroll
        for (int mt = 0; mt < 4; ++mt) {
            #pragma unroll
            for (int reg = 0; reg < 4; ++reg) {
                int lrow = mt * 16 + quad * 4 + reg;
                float v = (acc[mt][nt][reg] + bsum) * msk[lrow];
                tr[lrow * TR_STRIDE + col] = v;
                s[nt] += v;
                ss[nt] += v * v;
            }
        }
    }
    #pragma unroll
    for (int nt = 0; nt < 2; ++nt) {
        s[nt]  += __shfl_xor(s[nt], 16);  s[nt]  += __shfl_xor(s[nt], 32);
        ss[nt] += __shfl_xor(ss[nt], 16); ss[nt] += __shfl_xor(ss[nt], 32);
    }
    int slot = blockIdx.x & (NSLOT - 1);
    if (lane < 16) {
        #pragma unroll
        for (int nt = 0; nt < 2; ++nt) {
            int col = colbase + nt * 16 + lane;
            atomicAdd(&gstats[slot * 2 * H + col],     s[nt]);
            atomicAdd(&gstats[slot * 2 * H + H + col], ss[nt]);
        }
    }
    __syncthreads();

    for (int i = t; i < 64 * 16; i += 256) {
        int row = i >> 4, g = i & 15;
        const float* src = tr + row * TR_STRIDE + g * 8;
        float tmp[8];
        float4 v0 = ((const float4*)src)[0];
        float4 v1 = ((const float4*)src)[1];
        tmp[0]=v0.x; tmp[1]=v0.y; tmp[2]=v0.z; tmp[3]=v0.w;
        tmp[4]=v1.x; tmp[5]=v1.y; tmp[6]=v1.z; tmp[7]=v1.w;
        *((uint4*)(hnb + (size_t)(r0 + row) * H + g * 8)) = pack8(tmp);
    }
}

// ------------- BN stats finalize -------------
__global__ void k_bnstats(const float* __restrict__ gstats,
                          const float* __restrict__ g, const float* __restrict__ b,
                          float* __restrict__ scl, float* __restrict__ sft)
{
    int c = threadIdx.x;
    float s = 0.f, ss = 0.f;
    for (int i = 0; i < NSLOT; ++i) {
        s  += gstats[i * 2 * H + c];
        ss += gstats[i * 2 * H + H + c];
    }
    const float invR = 1.f / (float)RTOT;
    float mean = s * invR;
    float var  = ss * invR - mean * mean;
    float inv  = rsqrtf(var + BNEPS);
    float sc   = g[c] * inv;
    scl[c] = sc;
    sft[c] = fmaf(-mean, sc, b[c]);
}

// ------------- h += relu(hn*scl + sft) -------------
__global__ __launch_bounds__(256) void k_norm_res(
    const ushort_t* __restrict__ hnb, const float* __restrict__ scl,
    const float* __restrict__ sft, ushort_t* __restrict__ hb)
{
    int idx = blockIdx.x * 256 + threadIdx.x;
    int row = idx >> 4;
    int g   = idx & 15;
    uint4 pn = *((const uint4*)(hnb + (size_t)row * H + g * 8));
    uint4 ph = *((const uint4*)(hb  + (size_t)row * H + g * 8));
    float vn[8], vh[8];
    unpack8(pn, vn);
    unpack8(ph, vh);
    float4 s0 = ((const float4*)scl)[g * 2], s1 = ((const float4*)scl)[g * 2 + 1];
    float4 f0 = ((const float4*)sft)[g * 2], f1 = ((const float4*)sft)[g * 2 + 1];
    float sa[8] = {s0.x,s0.y,s0.z,s0.w,s1.x,s1.y,s1.z,s1.w};
    float fa[8] = {f0.x,f0.y,f0.z,f0.w,f1.x,f1.y,f1.z,f1.w};
    #pragma unroll
    for (int e = 0; e < 8; ++e)
        vh[e] += fmaxf(fmaf(vn[e], sa[e], fa[e]), 0.f);
    *((uint4*)(hb + (size_t)row * H + g * 8)) = pack8(vh);
}

// ------------- MFMA head: out = (relu(h@W1 + b1) @ W2 + b2) * m -------------
// 64 rows/block, 4 waves (wave = 16-row M-tile). W1 converted fp32->bf16 B^T
// in LDS at staging (no d_out scratch reads -> no race with out writes).
__global__ __launch_bounds__(256) void k_head(
    const ushort_t* __restrict__ hb, const float* __restrict__ W1,
    const float* __restrict__ b1, const float* __restrict__ W2,
    const float* __restrict__ b2, const float* __restrict__ mask,
    float* __restrict__ out)
{
    __shared__ ushort_t hs [64 * HS_STRIDE];   // h rows, bf16
    __shared__ ushort_t w1t[64 * HS_STRIDE];   // W1^T [n][k], bf16, padded
    const int t    = threadIdx.x;
    const int wave = t >> 6;
    const int lane = t & 63;
    const int l15  = lane & 15;
    const int quad = lane >> 4;
    const int r0   = blockIdx.x * NPB;

    for (int i = t; i < 64 * 16; i += 256) {
        int row = i >> 4, g = i & 15;
        *((uint4*)(hs + row * HS_STRIDE + g * 8)) =
            *((const uint4*)(hb + (size_t)(r0 + row) * H + g * 8));
    }
    for (int i = t; i < H * 64; i += 256) {    // W1[k][n] fp32 -> w1t[n][k] bf16
        int k = i >> 6, n = i & 63;
        w1t[n * HS_STRIDE + k] = f2bf(W1[i]);
    }
    __syncthreads();

    f32x4 acc[4];
    #pragma unroll
    for (int nt = 0; nt < 4; ++nt) acc[nt] = (f32x4){0.f, 0.f, 0.f, 0.f};

    #pragma unroll
    for (int ks = 0; ks < 4; ++ks) {
        short8 a = *((const short8*)(hs + (wave * 16 + l15) * HS_STRIDE + ks * 32 + quad * 8));
        #pragma unroll
        for (int nt = 0; nt < 4; ++nt) {
            short8 b = *((const short8*)(w1t + (nt * 16 + l15) * HS_STRIDE + ks * 32 + quad * 8));
            acc[nt] = __builtin_amdgcn_mfma_f32_16x16x32_bf16(a, b, acc[nt], 0, 0, 0);
        }
    }

    float p0[4] = {0,0,0,0}, p1[4] = {0,0,0,0};
    #pragma unroll
    for (int nt = 0; nt < 4; ++nt) {
        int col = nt * 16 + l15;
        float bb = b1[col];
        float wa = W2[2 * col], wb = W2[2 * col + 1];
        #pragma unroll
        for (int reg = 0; reg < 4; ++reg) {
            float v = fmaxf(acc[nt][reg] + bb, 0.f);
            p0[reg] = fmaf(v, wa, p0[reg]);
            p1[reg] = fmaf(v, wb, p1[reg]);
        }
    }
    #pragma unroll
    for (int reg = 0; reg < 4; ++reg) {
        p0[reg] += __shfl_xor(p0[reg], 1); p0[reg] += __shfl_xor(p0[reg], 2);
        p0[reg] += __shfl_xor(p0[reg], 4); p0[reg] += __shfl_xor(p0[reg], 8);
        p1[reg] += __shfl_xor(p1[reg], 1); p1[reg] += __shfl_xor(p1[reg], 2);
        p1[reg] += __shfl_xor(p1[reg], 4); p1[reg] += __shfl_xor(p1[reg], 8);
    }
    if (l15 == 0) {
        #pragma unroll
        for (int reg = 0; reg < 4; ++reg) {
            int gr = r0 + wave * 16 + quad * 4 + reg;
            float m = mask[gr];
            float2 o;
            o.x = (p0[reg] + b2[0]) * m;
            o.y = (p1[reg] + b2[1]) * m;
            *((float2*)(out + 2 * gr)) = o;
        }
    }
}

extern "C" void kernel_launch(void* const* d_in, const int* in_sizes, int n_in,
                              void* d_out, int out_size, void* d_ws, size_t ws_size,
                              hipStream_t stream)
{
    const float* x     = (const float*)d_in[0];
    const float* mask  = (const float*)d_in[1];
    const float* emb_w = (const float*)d_in[2];
    const float* emb_b = (const float*)d_in[3];
    const float* lin_w = (const float*)d_in[4];
    const float* lin_b = (const float*)d_in[5];
    const float* nb_w  = (const float*)d_in[6];
    const float* nb_b  = (const float*)d_in[7];
    const float* bn_g  = (const float*)d_in[8];
    const float* bn_b  = (const float*)d_in[9];
    const float* o1w   = (const float*)d_in[10];
    const float* o1b   = (const float*)d_in[11];
    const float* o2w   = (const float*)d_in[12];
    const float* o2b   = (const float*)d_in[13];
    float* out = (float*)d_out;

    char* ws = (char*)d_ws;
    ushort_t* hb  = (ushort_t*)ws;
    ushort_t* hnb = (ushort_t*)(ws + (size_t)RTOT * H * 2);

    // Scratch in d_out: consumed only by conv/bnstats/norm, all of which
    // complete before k_head overwrites d_out with the real output.
    float* gst = (float*)d_out;
    float* scl = gst + NLAYER * NSLOT * 2 * H;
    float* sft = scl + NLAYER * H;
    ushort_t* Wlt = (ushort_t*)((float*)d_out + 65536);
    ushort_t* Wnt = Wlt + NLAYER * H * H;

    hipMemsetAsync(gst, 0, NLAYER * NSLOT * 2 * H * sizeof(float), stream);

    k_prep<<<384, 256, 0, stream>>>(lin_w, nb_w, Wlt, Wnt);
    k_embed<<<RTOT * HV / 256, 256, 0, stream>>>(x, emb_w, emb_b, hb);
    for (int i = 0; i < NLAYER; ++i) {
        k_conv<<<RTOT / NPB, 256, 0, stream>>>(
            hb, Wlt + i * H * H, Wnt + i * H * H,
            lin_b + i * H, nb_b + i * H, mask,
            hnb, gst + i * NSLOT * 2 * H);
        k_bnstats<<<1, H, 0, stream>>>(
            gst + i * NSLOT * 2 * H, bn_g + i * H, bn_b + i * H,
            scl + i * H, sft + i * H);
        k_norm_res<<<RTOT * H / 8 / 256, 256, 0, stream>>>(
            hnb, scl + i * H, sft + i * H, hb);
    }
    k_head<<<RTOT / NPB, 256, 0, stream>>>(hb, o1w, o1b, o2w, o2b, mask, out);
}

// Round 5
// 395.136 us; speedup vs baseline: 2.4768x; 1.0033x over previous
//
#include <hip/hip_runtime.h>
#include <cstddef>

#define H      128
#define HV     32
#define NBATCH 32
#define NN     8192
#define RTOT   (NBATCH*NN) // 262144 rows
#define NLAYER 3
#define BNEPS  1e-5f
#define NSLOT  16
#define NPB    64          // rows per conv/head block (divides NN)
#define HS_STRIDE 136      // fp16 elems per LDS row (128 + 8 pad)

typedef _Float16 f16;
typedef __attribute__((ext_vector_type(8))) _Float16 half8;  // 8 fp16 (4 VGPRs)
typedef __attribute__((ext_vector_type(4))) float f32x4;     // MFMA C/D

__device__ __forceinline__ void unpackh8(uint4 pk, float* d) {
    const f16* hp = (const f16*)&pk;
    #pragma unroll
    for (int i = 0; i < 8; ++i) d[i] = (float)hp[i];
}
__device__ __forceinline__ uint4 packh8(const float* s) {
    uint4 pk;
    f16* hp = (f16*)&pk;
    #pragma unroll
    for (int i = 0; i < 8; ++i) hp[i] = (f16)s[i];
    return pk;
}

// ---- weight prep: fp32 W[l][k][n] -> fp16 Wt[l][n][k] (B^T fragment layout) ----
__global__ __launch_bounds__(256) void k_prep(
    const float* __restrict__ lin_w, const float* __restrict__ nb_w,
    f16* __restrict__ Wlt, f16* __restrict__ Wnt)
{
    int id = blockIdx.x * 256 + threadIdx.x;    // 2*3*128*128 = 98304 total
    int mat = id / 49152;
    int r   = id - mat * 49152;
    int l   = r >> 14;
    int r2  = r & 16383;
    int k   = r2 >> 7;
    int n   = r2 & 127;
    const float* src = mat ? nb_w : lin_w;
    f16*         dst = mat ? Wnt  : Wlt;
    dst[l * 16384 + n * 128 + k] = (f16)src[l * 16384 + k * 128 + n];
}

// ---------------- embedding: h = x @ emb_w + emb_b  (h stored fp16) ----------------
__global__ __launch_bounds__(256) void k_embed(
    const float* __restrict__ x, const float* __restrict__ ew,
    const float* __restrict__ eb, f16* __restrict__ hb)
{
    int idx = blockIdx.x * 256 + threadIdx.x;   // one 4-channel group
    int r  = idx >> 5;
    int cv = idx & 31;
    float x0 = x[2 * r], x1 = x[2 * r + 1];
    float4 w0 = ((const float4*)ew)[cv];
    float4 w1 = ((const float4*)ew)[HV + cv];
    float4 bb = ((const float4*)eb)[cv];
    uint2 st;
    f16* sp = (f16*)&st;
    sp[0] = (f16)fmaf(x1, w1.x, fmaf(x0, w0.x, bb.x));
    sp[1] = (f16)fmaf(x1, w1.y, fmaf(x0, w0.y, bb.y));
    sp[2] = (f16)fmaf(x1, w1.z, fmaf(x0, w0.z, bb.z));
    sp[3] = (f16)fmaf(x1, w1.w, fmaf(x0, w0.w, bb.w));
    *((uint2*)(hb + (size_t)r * H + cv * 4)) = st;
}

// ------------- MFMA graph conv + BN stats (fp16, on-the-fly nsum) -------------
// Block: 64 rows x 128 cols, 4 waves (each wave: 64 rows x 32 cols).
__global__ __launch_bounds__(256) void k_conv(
    const f16* __restrict__ hb,
    const f16* __restrict__ Wlt, const f16* __restrict__ Wnt,
    const float* __restrict__ bl, const float* __restrict__ bnb,
    const float* __restrict__ mask,
    f16* __restrict__ hnb, float* __restrict__ gstats)
{
    // union: hs (66 rows fp16) during MFMA phase; tr (64 rows fp16) after.
    __shared__ __align__(16) f16 smem[66 * HS_STRIDE];
    __shared__ float msk[NPB];
    f16* hs = smem;                    // rows r0-1 .. r0+64
    f16* tr = smem;                    // 64 x HS_STRIDE (reuse after barrier)

    const int t    = threadIdx.x;
    const int wave = t >> 6;
    const int lane = t & 63;
    const int l15  = lane & 15;
    const int quad = lane >> 4;
    const int r0   = blockIdx.x * NPB;
    const int batch = r0 / NN;
    const int n0   = r0 - batch * NN;

    // B fragments: Wt[n][k], lane reads 8 contiguous k at row nbase+l15
    const int colbase = wave * 32;
    half8 bWl[2][4], bWn[2][4];
    #pragma unroll
    for (int nt = 0; nt < 2; ++nt) {
        int nrow = colbase + nt * 16 + l15;
        #pragma unroll
        for (int ks = 0; ks < 4; ++ks) {
            int off = nrow * 128 + ks * 32 + quad * 8;
            bWl[nt][ks] = *((const half8*)(Wlt + off));
            bWn[nt][ks] = *((const half8*)(Wnt + off));
        }
    }

    // stage h rows (fp16, padded stride)
    for (int i = t; i < 66 * 16; i += 256) {
        int row = i >> 4, g = i & 15;
        int n = n0 + row - 1;
        n = (n + NN) & (NN - 1);       // ring wrap within batch
        uint4 pk = *((const uint4*)(hb + ((size_t)(batch * NN + n)) * H + g * 8));
        *((uint4*)(hs + row * HS_STRIDE + g * 8)) = pk;
    }
    if (t < NPB) msk[t] = mask[r0 + t];
    __syncthreads();

    // MFMA K-loop; nsum fragments built on the fly with packed fp16 adds
    f32x4 acc[4][2];
    #pragma unroll
    for (int mt = 0; mt < 4; ++mt)
        #pragma unroll
        for (int nt = 0; nt < 2; ++nt)
            acc[mt][nt] = (f32x4){0.f, 0.f, 0.f, 0.f};

    #pragma unroll
    for (int ks = 0; ks < 4; ++ks) {
        half8 as[4], an[4];
        #pragma unroll
        for (int mt = 0; mt < 4; ++mt) {
            int row = mt * 16 + l15;
            const f16* base = hs + row * HS_STRIDE + ks * 32 + quad * 8;
            half8 hm = *((const half8*)(base + HS_STRIDE));       // row
            half8 hd = *((const half8*)(base));                   // row-1
            half8 hu = *((const half8*)(base + 2 * HS_STRIDE));   // row+1
            as[mt] = hm;
            an[mt] = hd + hu;            // v_pk_add_f16 x4
        }
        #pragma unroll
        for (int nt = 0; nt < 2; ++nt)
            #pragma unroll
            for (int mt = 0; mt < 4; ++mt)
                acc[mt][nt] = __builtin_amdgcn_mfma_f32_16x16x32_f16(
                    as[mt], bWl[nt][ks], acc[mt][nt], 0, 0, 0);
        #pragma unroll
        for (int nt = 0; nt < 2; ++nt)
            #pragma unroll
            for (int mt = 0; mt < 4; ++mt)
                acc[mt][nt] = __builtin_amdgcn_mfma_f32_16x16x32_f16(
                    an[mt], bWn[nt][ks], acc[mt][nt], 0, 0, 0);
    }
    __syncthreads();   // hs dead; tr may overwrite

    // epilogue: bias + mask, BN partials, transpose via LDS (fp16)
    float s[2] = {0.f, 0.f}, ss[2] = {0.f, 0.f};
    #pragma unroll
    for (int nt = 0; nt < 2; ++nt) {
        int col = colbase + nt * 16 + l15;
        float bsum = bl[col] + bnb[col];
        #pragma unroll
        for (int mt = 0; mt < 4; ++mt) {
            #pragma unroll
            for (int reg = 0; reg < 4; ++reg) {
                int lrow = mt * 16 + quad * 4 + reg;
                float v = (acc[mt][nt][reg] + bsum) * msk[lrow];
                tr[lrow * HS_STRIDE + col] = (f16)v;
                s[nt] += v;
                ss[nt] += v * v;
            }
        }
    }
    #pragma unroll
    for (int nt = 0; nt < 2; ++nt) {
        s[nt]  += __shfl_xor(s[nt], 16);  s[nt]  += __shfl_xor(s[nt], 32);
        ss[nt] += __shfl_xor(ss[nt], 16); ss[nt] += __shfl_xor(ss[nt], 32);
    }
    int slot = blockIdx.x & (NSLOT - 1);
    if (lane < 16) {
        #pragma unroll
        for (int nt = 0; nt < 2; ++nt) {
            int col = colbase + nt * 16 + lane;
            atomicAdd(&gstats[slot * 2 * H + col],     s[nt]);
            atomicAdd(&gstats[slot * 2 * H + H + col], ss[nt]);
        }
    }
    __syncthreads();

    // coalesced fp16 writeback
    for (int i = t; i < 64 * 16; i += 256) {
        int row = i >> 4, g = i & 15;
        *((uint4*)(hnb + (size_t)(r0 + row) * H + g * 8)) =
            *((const uint4*)(tr + row * HS_STRIDE + g * 8));
    }
}

// ------------- norm+relu+residual, BN finalize inlined per block -------------
__global__ __launch_bounds__(256) void k_norm(
    const f16* __restrict__ hnb, const float* __restrict__ gstats,
    const float* __restrict__ bn_g, const float* __restrict__ bn_b,
    f16* __restrict__ hb)
{
    __shared__ float scl_s[H], sft_s[H];
    const int t = threadIdx.x;
    if (t < H) {
        float s = 0.f, ss = 0.f;
        #pragma unroll
        for (int i = 0; i < NSLOT; ++i) {
            s  += gstats[i * 2 * H + t];
            ss += gstats[i * 2 * H + H + t];
        }
        const float invR = 1.f / (float)RTOT;
        float mean = s * invR;
        float var  = ss * invR - mean * mean;
        float inv  = rsqrtf(var + BNEPS);
        float sc   = bn_g[t] * inv;
        scl_s[t] = sc;
        sft_s[t] = fmaf(-mean, sc, bn_b[t]);
    }
    __syncthreads();

    for (size_t idx = (size_t)blockIdx.x * 256 + t; idx < (size_t)RTOT * 16;
         idx += (size_t)gridDim.x * 256) {
        size_t row = idx >> 4;
        int g = idx & 15;
        uint4 pn = *((const uint4*)(hnb + row * H + g * 8));
        uint4 ph = *((const uint4*)(hb  + row * H + g * 8));
        float vn[8], vh[8];
        unpackh8(pn, vn);
        unpackh8(ph, vh);
        #pragma unroll
        for (int e = 0; e < 8; ++e) {
            int c = g * 8 + e;
            vh[e] += fmaxf(fmaf(vn[e], scl_s[c], sft_s[c]), 0.f);
        }
        *((uint4*)(hb + row * H + g * 8)) = packh8(vh);
    }
}

// ------------- MFMA head: out = (relu(h@W1 + b1) @ W2 + b2) * m -------------
__global__ __launch_bounds__(256) void k_head(
    const f16* __restrict__ hb, const float* __restrict__ W1,
    const float* __restrict__ b1, const float* __restrict__ W2,
    const float* __restrict__ b2, const float* __restrict__ mask,
    float* __restrict__ out)
{
    __shared__ f16 hs [64 * HS_STRIDE];   // h rows, fp16
    __shared__ f16 w1t[64 * HS_STRIDE];   // W1^T [n][k], fp16, padded
    const int t    = threadIdx.x;
    const int wave = t >> 6;
    const int lane = t & 63;
    const int l15  = lane & 15;
    const int quad = lane >> 4;
    const int r0   = blockIdx.x * NPB;

    for (int i = t; i < 64 * 16; i += 256) {
        int row = i >> 4, g = i & 15;
        *((uint4*)(hs + row * HS_STRIDE + g * 8)) =
            *((const uint4*)(hb + (size_t)(r0 + row) * H + g * 8));
    }
    for (int i = t; i < H * 64; i += 256) {    // W1[k][n] fp32 -> w1t[n][k] fp16
        int k = i >> 6, n = i & 63;
        w1t[n * HS_STRIDE + k] = (f16)W1[i];
    }
    __syncthreads();

    f32x4 acc[4];
    #pragma unroll
    for (int nt = 0; nt < 4; ++nt) acc[nt] = (f32x4){0.f, 0.f, 0.f, 0.f};

    #pragma unroll
    for (int ks = 0; ks < 4; ++ks) {
        half8 a = *((const half8*)(hs + (wave * 16 + l15) * HS_STRIDE + ks * 32 + quad * 8));
        #pragma unroll
        for (int nt = 0; nt < 4; ++nt) {
            half8 b = *((const half8*)(w1t + (nt * 16 + l15) * HS_STRIDE + ks * 32 + quad * 8));
            acc[nt] = __builtin_amdgcn_mfma_f32_16x16x32_f16(a, b, acc[nt], 0, 0, 0);
        }
    }

    float p0[4] = {0,0,0,0}, p1[4] = {0,0,0,0};
    #pragma unroll
    for (int nt = 0; nt < 4; ++nt) {
        int col = nt * 16 + l15;
        float bb = b1[col];
        float wa = W2[2 * col], wb = W2[2 * col + 1];
        #pragma unroll
        for (int reg = 0; reg < 4; ++reg) {
            float v = fmaxf(acc[nt][reg] + bb, 0.f);
            p0[reg] = fmaf(v, wa, p0[reg]);
            p1[reg] = fmaf(v, wb, p1[reg]);
        }
    }
    #pragma unroll
    for (int reg = 0; reg < 4; ++reg) {
        p0[reg] += __shfl_xor(p0[reg], 1); p0[reg] += __shfl_xor(p0[reg], 2);
        p0[reg] += __shfl_xor(p0[reg], 4); p0[reg] += __shfl_xor(p0[reg], 8);
        p1[reg] += __shfl_xor(p1[reg], 1); p1[reg] += __shfl_xor(p1[reg], 2);
        p1[reg] += __shfl_xor(p1[reg], 4); p1[reg] += __shfl_xor(p1[reg], 8);
    }
    if (l15 == 0) {
        #pragma unroll
        for (int reg = 0; reg < 4; ++reg) {
            int gr = r0 + wave * 16 + quad * 4 + reg;
            float m = mask[gr];
            float2 o;
            o.x = (p0[reg] + b2[0]) * m;
            o.y = (p1[reg] + b2[1]) * m;
            *((float2*)(out + 2 * gr)) = o;
        }
    }
}

extern "C" void kernel_launch(void* const* d_in, const int* in_sizes, int n_in,
                              void* d_out, int out_size, void* d_ws, size_t ws_size,
                              hipStream_t stream)
{
    const float* x     = (const float*)d_in[0];
    const float* mask  = (const float*)d_in[1];
    const float* emb_w = (const float*)d_in[2];
    const float* emb_b = (const float*)d_in[3];
    const float* lin_w = (const float*)d_in[4];
    const float* lin_b = (const float*)d_in[5];
    const float* nb_w  = (const float*)d_in[6];
    const float* nb_b  = (const float*)d_in[7];
    const float* bn_g  = (const float*)d_in[8];
    const float* bn_b  = (const float*)d_in[9];
    const float* o1w   = (const float*)d_in[10];
    const float* o1b   = (const float*)d_in[11];
    const float* o2w   = (const float*)d_in[12];
    const float* o2b   = (const float*)d_in[13];
    float* out = (float*)d_out;

    // Workspace: h (fp16, 64 MiB) + hn (fp16, 64 MiB) = 128 MiB.
    char* ws = (char*)d_ws;
    f16* hb  = (f16*)ws;
    f16* hnb = (f16*)(ws + (size_t)RTOT * H * 2);

    // Scratch in d_out (2 MiB; consumed before k_head overwrites it):
    // [0, 12288) floats: gstats; from float offset 65536: fp16 Wlt/Wnt.
    float* gst = (float*)d_out;
    f16* Wlt = (f16*)((float*)d_out + 65536);   // 3*128*128 fp16
    f16* Wnt = Wlt + NLAYER * H * H;

    hipMemsetAsync(gst, 0, NLAYER * NSLOT * 2 * H * sizeof(float), stream);

    k_prep<<<384, 256, 0, stream>>>(lin_w, nb_w, Wlt, Wnt);
    k_embed<<<RTOT * HV / 256, 256, 0, stream>>>(x, emb_w, emb_b, hb);
    for (int i = 0; i < NLAYER; ++i) {
        k_conv<<<RTOT / NPB, 256, 0, stream>>>(
            hb, Wlt + i * H * H, Wnt + i * H * H,
            lin_b + i * H, nb_b + i * H, mask,
            hnb, gst + i * NSLOT * 2 * H);
        k_norm<<<2048, 256, 0, stream>>>(
            hnb, gst + i * NSLOT * 2 * H, bn_g + i * H, bn_b + i * H, hb);
    }
    k_head<<<RTOT / NPB, 256, 0, stream>>>(hb, o1w, o1b, o2w, o2b, mask, out);
}